// Round 1
// baseline (1448.429 us; speedup 1.0000x reference)
//
#include <hip/hip_runtime.h>
#include <math.h>

namespace {
constexpr int kS  = 2048;
constexpr int kD  = 64;
constexpr int kBH = 2 * 16;        // B*H
constexpr int kNR = kBH * kS;      // total q rows = 65536
constexpr float kScaleLog2e = 0.125f * 1.44269504088896340736f; // rsqrt(64)*log2(e)
}

// One wave (64 lanes) per block. Lane l owns q-row qt*64+l.
// K/V row addresses are wave-uniform -> scalar-broadcast loads.
// Online softmax in base-2 domain (scale*log2e folded into Q).
__global__ __launch_bounds__(64)
void attn_fwd_partial(const float* __restrict__ Q,
                      const float* __restrict__ K,
                      const float* __restrict__ V,
                      float* __restrict__ out,     // used when nsplit==1
                      float* __restrict__ ws_out,  // [nsplit][kNR][kD]
                      float* __restrict__ ws_ml,   // [nsplit][kNR][2]
                      int nsplit)
{
    const int lane = threadIdx.x;
    const int qt   = blockIdx.x;   // q tile, 0..31
    const int bh   = blockIdx.y;   // 0..31
    const int sp   = blockIdx.z;   // split index

    const int q     = qt * 64 + lane;
    const int chunk = kS / nsplit;
    const int k0    = sp * chunk;
    const int k1    = min((sp + 1) * chunk, qt * 64 + 64);  // causal upper bound for this tile

    const size_t base = (size_t)bh * kS * kD;
    const float* __restrict__ Qrow = Q + base + (size_t)q * kD;
    const float* __restrict__ Kb   = K + base;
    const float* __restrict__ Vb   = V + base;

    // Q row in registers, pre-scaled into base-2 domain
    float qv[kD];
    #pragma unroll
    for (int i = 0; i < kD / 4; ++i) {
        float4 t = reinterpret_cast<const float4*>(Qrow)[i];
        qv[4*i+0] = t.x * kScaleLog2e;
        qv[4*i+1] = t.y * kScaleLog2e;
        qv[4*i+2] = t.z * kScaleLog2e;
        qv[4*i+3] = t.w * kScaleLog2e;
    }

    float acc[kD];
    #pragma unroll
    for (int d = 0; d < kD; ++d) acc[d] = 0.f;
    float m = -INFINITY;
    float l = 0.f;

    for (int k = k0; k < k1; ++k) {
        const float4* __restrict__ Kr = reinterpret_cast<const float4*>(Kb + (size_t)k * kD);
        const float4* __restrict__ Vr = reinterpret_cast<const float4*>(Vb + (size_t)k * kD);

        // dot(Q[q], K[k]) with 4-way ILP
        float s0 = 0.f, s1 = 0.f, s2 = 0.f, s3 = 0.f;
        #pragma unroll
        for (int i = 0; i < kD / 4; ++i) {
            float4 kk = Kr[i];
            s0 = fmaf(qv[4*i+0], kk.x, s0);
            s1 = fmaf(qv[4*i+1], kk.y, s1);
            s2 = fmaf(qv[4*i+2], kk.z, s2);
            s3 = fmaf(qv[4*i+3], kk.w, s3);
        }
        const float s = (s0 + s1) + (s2 + s3);

        const bool  act = (k <= q);            // causal mask, branchless via p=0
        const float mn  = act ? fmaxf(m, s) : m;
        const float p   = act ? exp2f(s - mn) : 0.f;
        if (mn > m) {                          // rare (max grew): rescale
            const float alpha = exp2f(m - mn); // ==0 when m was -inf
            l *= alpha;
            #pragma unroll
            for (int d = 0; d < kD; ++d) acc[d] *= alpha;
            m = mn;
        }
        l += p;
        #pragma unroll
        for (int i = 0; i < kD / 4; ++i) {
            float4 vv = Vr[i];
            acc[4*i+0] = fmaf(p, vv.x, acc[4*i+0]);
            acc[4*i+1] = fmaf(p, vv.y, acc[4*i+1]);
            acc[4*i+2] = fmaf(p, vv.z, acc[4*i+2]);
            acc[4*i+3] = fmaf(p, vv.w, acc[4*i+3]);
        }
    }

    if (nsplit == 1) {
        const float inv = 1.0f / l;            // l>0: k=0..q always non-empty
        float* __restrict__ orow = out + base + (size_t)q * kD;
        #pragma unroll
        for (int i = 0; i < kD / 4; ++i) {
            float4 t;
            t.x = acc[4*i+0] * inv;
            t.y = acc[4*i+1] * inv;
            t.z = acc[4*i+2] * inv;
            t.w = acc[4*i+3] * inv;
            reinterpret_cast<float4*>(orow)[i] = t;
        }
    } else {
        const size_t r = (size_t)bh * kS + (size_t)q;
        float* __restrict__ wrow = ws_out + ((size_t)sp * kNR + r) * kD;
        #pragma unroll
        for (int i = 0; i < kD / 4; ++i) {
            float4 t;
            t.x = acc[4*i+0];
            t.y = acc[4*i+1];
            t.z = acc[4*i+2];
            t.w = acc[4*i+3];
            reinterpret_cast<float4*>(wrow)[i] = t;
        }
        float* wml = ws_ml + ((size_t)sp * kNR + r) * 2;
        wml[0] = m;
        wml[1] = l;
    }
}

// Combine split-K partials: one thread per (row, d).
__global__ __launch_bounds__(256)
void attn_merge(const float* __restrict__ ws_out,
                const float* __restrict__ ws_ml,
                float* __restrict__ out,
                int nsplit)
{
    const int tid = blockIdx.x * 256 + threadIdx.x;
    const int r   = tid >> 6;
    const int d   = tid & 63;
    if (r >= kNR) return;

    float M = -INFINITY;
    for (int p = 0; p < nsplit; ++p)
        M = fmaxf(M, ws_ml[((size_t)p * kNR + r) * 2]);

    float num = 0.f, den = 0.f;
    for (int p = 0; p < nsplit; ++p) {
        const float2 ml = reinterpret_cast<const float2*>(ws_ml + ((size_t)p * kNR + r) * 2)[0];
        const float a = exp2f(ml.x - M);       // 0 for empty splits (ml.x==-inf)
        num = fmaf(a, ws_out[((size_t)p * kNR + r) * (size_t)kD + d], num);
        den = fmaf(a, ml.y, den);
    }
    out[(size_t)r * kD + d] = num / den;
}

extern "C" void kernel_launch(void* const* d_in, const int* in_sizes, int n_in,
                              void* d_out, int out_size, void* d_ws, size_t ws_size,
                              hipStream_t stream) {
    const float* Q = (const float*)d_in[0];
    const float* K = (const float*)d_in[1];
    const float* V = (const float*)d_in[2];
    // d_in[3] is the causal mask; causality is implemented directly.
    float* out = (float*)d_out;

    // Split-K factor chosen from available workspace (fallback: monolithic).
    const size_t per_split = (size_t)kNR * (kD + 2) * sizeof(float);
    int nsplit = 1;
    if      (ws_size >= 4 * per_split) nsplit = 4;
    else if (ws_size >= 2 * per_split) nsplit = 2;

    float* ws_out = (float*)d_ws;
    float* ws_ml  = ws_out + (size_t)nsplit * kNR * kD;

    dim3 grid(kS / 64, kBH, nsplit);
    attn_fwd_partial<<<grid, 64, 0, stream>>>(Q, K, V, out, ws_out, ws_ml, nsplit);

    if (nsplit > 1) {
        const int total = kNR * kD;
        attn_merge<<<(total + 255) / 256, 256, 0, stream>>>(ws_out, ws_ml, out, nsplit);
    }
}

// Round 2
// 201.654 us; speedup vs baseline: 7.1827x; 7.1827x over previous
//
#include <hip/hip_runtime.h>
#include <math.h>

typedef __attribute__((ext_vector_type(8))) short bf16x8;
typedef __attribute__((ext_vector_type(4))) short s16x4;
typedef __attribute__((ext_vector_type(4))) float f32x4;

namespace {
constexpr int kS   = 2048;
constexpr int kD   = 64;
constexpr int KPAD = 72;   // 72*2B = 144B = 9 x 16B granules -> balanced LDS banks
constexpr float kScaleLog2e = 0.125f * 1.44269504088896340736f; // rsqrt(64)*log2(e)
}

__device__ __forceinline__ short f2bf(float f) {
    union { float f; unsigned u; } c; c.f = f;
    unsigned r = c.u + 0x7fffu + ((c.u >> 16) & 1u);   // round-to-nearest-even
    return (short)(r >> 16);
}

// Block = 4 waves (256 thr). Block handles 64 q rows of one (b,h); wave w owns
// rows [qt*64 + w*16, +16). KV staged per 64-key tile: K as bf16 [64][KPAD]
// row-major, V transposed [d][KPAD]. mfma_f32_16x16x32_bf16 for S and PV.
// A-frag: row=lane&15, k=(lane>>4)*8+j. B-frag: col=lane&15, k=(lane>>4)*8+j.
// C/D:    col=lane&15, row=(lane>>4)*4+reg  (m89-verified).
__global__ __launch_bounds__(256)
void attn_mfma(const float* __restrict__ Q, const float* __restrict__ K,
               const float* __restrict__ V, float* __restrict__ O)
{
    __shared__ short Klds[64 * KPAD];
    __shared__ short VTlds[64 * KPAD];
    __shared__ short Plds[4 * 16 * KPAD];

    const int tid  = threadIdx.x;
    const int lane = tid & 63;
    const int w    = tid >> 6;
    const int lo   = lane & 15;
    const int hi   = lane >> 4;

    const int qt = (int)gridDim.x - 1 - (int)blockIdx.x;  // big blocks first
    const int bh = blockIdx.y;

    const size_t hbase = (size_t)bh * kS * kD;

    // ---- Q A-fragments (hoisted): lane holds Q[q=lo][d = dc*32 + hi*8 + j],
    // pre-scaled into base-2 softmax domain.
    const float* Qr = Q + hbase + (size_t)(qt * 64 + w * 16 + lo) * kD;
    bf16x8 qfrag[2];
    #pragma unroll
    for (int dc = 0; dc < 2; ++dc) {
        const float4 a = *reinterpret_cast<const float4*>(Qr + dc * 32 + hi * 8);
        const float4 b = *reinterpret_cast<const float4*>(Qr + dc * 32 + hi * 8 + 4);
        bf16x8 f;
        f[0] = f2bf(a.x * kScaleLog2e); f[1] = f2bf(a.y * kScaleLog2e);
        f[2] = f2bf(a.z * kScaleLog2e); f[3] = f2bf(a.w * kScaleLog2e);
        f[4] = f2bf(b.x * kScaleLog2e); f[5] = f2bf(b.y * kScaleLog2e);
        f[6] = f2bf(b.z * kScaleLog2e); f[7] = f2bf(b.w * kScaleLog2e);
        qfrag[dc] = f;
    }

    const f32x4 zero4 = {0.f, 0.f, 0.f, 0.f};
    f32x4 o[4] = {zero4, zero4, zero4, zero4};      // o[dcB][r]: d=dcB*16+lo, q=hi*4+r
    float m_[4] = {-1e30f, -1e30f, -1e30f, -1e30f};
    float l_[4] = {0.f, 0.f, 0.f, 0.f};

    // staging coords: thread loads row sr, 16 cols starting sc (4 x float4)
    const int sr = tid >> 2;
    const int sc = (tid & 3) * 16;
    const float* Kg = K + hbase;
    const float* Vg = V + hbase;
    short* Pw = &Plds[w * 16 * KPAD];

    for (int kb = 0; kb <= qt; ++kb) {
        __syncthreads();   // previous tile fully consumed
        {
            const float* krow = Kg + (size_t)(kb * 64 + sr) * kD + sc;
            const float* vrow = Vg + (size_t)(kb * 64 + sr) * kD + sc;
            #pragma unroll
            for (int i = 0; i < 4; ++i) {
                const float4 kv = reinterpret_cast<const float4*>(krow)[i];
                s16x4 ks;
                ks[0] = f2bf(kv.x); ks[1] = f2bf(kv.y);
                ks[2] = f2bf(kv.z); ks[3] = f2bf(kv.w);
                *reinterpret_cast<s16x4*>(&Klds[sr * KPAD + sc + i * 4]) = ks;
                const float4 vv = reinterpret_cast<const float4*>(vrow)[i];
                VTlds[(sc + i * 4 + 0) * KPAD + sr] = f2bf(vv.x);
                VTlds[(sc + i * 4 + 1) * KPAD + sr] = f2bf(vv.y);
                VTlds[(sc + i * 4 + 2) * KPAD + sr] = f2bf(vv.z);
                VTlds[(sc + i * 4 + 3) * KPAD + sr] = f2bf(vv.w);
            }
        }
        __syncthreads();

        // ---- S strip: 16q x 64k = 4 kk-subtiles x 2 d-chunks of MFMA
        f32x4 sacc[4] = {zero4, zero4, zero4, zero4};
        #pragma unroll
        for (int kk = 0; kk < 4; ++kk) {
            #pragma unroll
            for (int dc = 0; dc < 2; ++dc) {
                const bf16x8 kf = *reinterpret_cast<const bf16x8*>(
                    &Klds[(kk * 16 + lo) * KPAD + dc * 32 + hi * 8]);
                sacc[kk] = __builtin_amdgcn_mfma_f32_16x16x32_bf16(
                    qfrag[dc], kf, sacc[kk], 0, 0, 0);
            }
        }

        // ---- causal mask on the diagonal tile (finite -inf: avoids NaN)
        if (kb == qt) {
            #pragma unroll
            for (int kk = 0; kk < 4; ++kk)
                #pragma unroll
                for (int r = 0; r < 4; ++r)
                    if (kk * 16 + lo > w * 16 + hi * 4 + r) sacc[kk][r] = -1e30f;
        }

        // ---- online softmax (base-2 domain; rows replicated over 16 lanes)
        float nm[4], alpha[4];
        #pragma unroll
        for (int r = 0; r < 4; ++r) {
            float v = fmaxf(fmaxf(sacc[0][r], sacc[1][r]),
                            fmaxf(sacc[2][r], sacc[3][r]));
            v = fmaxf(v, __shfl_xor(v, 1));
            v = fmaxf(v, __shfl_xor(v, 2));
            v = fmaxf(v, __shfl_xor(v, 4));
            v = fmaxf(v, __shfl_xor(v, 8));
            nm[r]    = fmaxf(v, m_[r]);
            alpha[r] = exp2f(m_[r] - nm[r]);
        }
        float p[4][4];
        #pragma unroll
        for (int kk = 0; kk < 4; ++kk)
            #pragma unroll
            for (int r = 0; r < 4; ++r)
                p[kk][r] = exp2f(sacc[kk][r] - nm[r]);
        #pragma unroll
        for (int r = 0; r < 4; ++r) {
            float s = (p[0][r] + p[1][r]) + (p[2][r] + p[3][r]);
            s += __shfl_xor(s, 1);
            s += __shfl_xor(s, 2);
            s += __shfl_xor(s, 4);
            s += __shfl_xor(s, 8);
            l_[r] = l_[r] * alpha[r] + s;
            m_[r] = nm[r];
        }
        #pragma unroll
        for (int dcB = 0; dcB < 4; ++dcB)
            #pragma unroll
            for (int r = 0; r < 4; ++r)
                o[dcB][r] *= alpha[r];

        // ---- P: D-layout -> A-layout via per-wave LDS strip (intra-wave only)
        #pragma unroll
        for (int kk = 0; kk < 4; ++kk)
            #pragma unroll
            for (int r = 0; r < 4; ++r)
                Pw[(hi * 4 + r) * KPAD + kk * 16 + lo] = f2bf(p[kk][r]);

        // ---- PV: O[16x64] += P[16x64] * V[64x64]
        #pragma unroll
        for (int kc = 0; kc < 2; ++kc) {
            const bf16x8 pf = *reinterpret_cast<const bf16x8*>(
                &Pw[lo * KPAD + kc * 32 + hi * 8]);
            #pragma unroll
            for (int dcB = 0; dcB < 4; ++dcB) {
                const bf16x8 vf = *reinterpret_cast<const bf16x8*>(
                    &VTlds[(dcB * 16 + lo) * KPAD + kc * 32 + hi * 8]);
                o[dcB] = __builtin_amdgcn_mfma_f32_16x16x32_bf16(
                    pf, vf, o[dcB], 0, 0, 0);
            }
        }
    }

    // ---- epilogue: normalize and store fp32
    float* Ob = O + hbase;
    #pragma unroll
    for (int r = 0; r < 4; ++r) {
        const float inv = 1.0f / l_[r];
        const size_t q = (size_t)(qt * 64 + w * 16 + hi * 4 + r);
        #pragma unroll
        for (int dcB = 0; dcB < 4; ++dcB)
            Ob[q * kD + dcB * 16 + lo] = o[dcB][r] * inv;
    }
}

extern "C" void kernel_launch(void* const* d_in, const int* in_sizes, int n_in,
                              void* d_out, int out_size, void* d_ws, size_t ws_size,
                              hipStream_t stream) {
    const float* Q = (const float*)d_in[0];
    const float* K = (const float*)d_in[1];
    const float* V = (const float*)d_in[2];
    // d_in[3] (causal mask) is static tril: causality implemented directly.
    float* out = (float*)d_out;
    (void)d_ws; (void)ws_size; (void)in_sizes; (void)n_in; (void)out_size;

    dim3 grid(kS / 64, 32);   // 32 q-tiles x (B*H)=32
    attn_mfma<<<grid, 256, 0, stream>>>(Q, K, V, out);
}

// Round 3
// 88.895 us; speedup vs baseline: 16.2937x; 2.2684x over previous
//
#include <hip/hip_runtime.h>
#include <math.h>

typedef __attribute__((ext_vector_type(8))) short bf16x8;
typedef __attribute__((ext_vector_type(8))) short s16x8;
typedef __attribute__((ext_vector_type(4))) short s16x4;
typedef __attribute__((ext_vector_type(4))) float f32x4;

namespace {
constexpr int kS   = 2048;
constexpr int kD   = 64;
constexpr int kBH  = 32;
constexpr int kT   = kS / 64;          // 32 KV/Q tiles
constexpr int PPAD = 72;               // P strip stride: 144B, 16B-aligned rows
constexpr float kScaleLog2e = 0.125f * 1.44269504088896340736f; // rsqrt(64)*log2(e)
}

__device__ __forceinline__ short f2bf(float f) {
    union { float f; unsigned u; } c; c.f = f;
    unsigned r = c.u + 0x7fffu + ((c.u >> 16) & 1u);   // RNE
    return (short)(r >> 16);
}

__device__ __forceinline__ s16x8 pack8(const float4& a, const float4& b) {
    s16x8 r;
    r[0] = f2bf(a.x); r[1] = f2bf(a.y); r[2] = f2bf(a.z); r[3] = f2bf(a.w);
    r[4] = f2bf(b.x); r[5] = f2bf(b.y); r[6] = f2bf(b.z); r[7] = f2bf(b.w);
    return r;
}

typedef const __attribute__((address_space(1))) void* gas_t;
typedef __attribute__((address_space(3))) void* las_t;
__device__ __forceinline__ void glds16(const void* g, void* l) {
    __builtin_amdgcn_global_load_lds((gas_t)g, (las_t)l, 16, 0, 0);
}

// ---------------- pre-pass: K -> bf16 swizzled, V -> V^T bf16 swizzled -------
// Swizzle: within each 128B row, 16B-granule g stored at g ^ (row & 7).
// Main kernel copies rows linearly into LDS (global_load_lds) and XORs the
// byte offset on ds_read -> conflict-free B-fragment reads (T2 / m201).
__global__ __launch_bounds__(256)
void prepack(const float* __restrict__ K, const float* __restrict__ V,
             short* __restrict__ wsK, short* __restrict__ wsVT)
{
    __shared__ float vt[64][65];
    const int tid = threadIdx.x;
    const int kb  = blockIdx.x;
    const int bh  = blockIdx.y;
    const int r   = tid >> 2;
    const int c0  = (tid & 3) * 16;

    const size_t grow = ((size_t)bh * kS + (size_t)kb * 64 + r) * kD + c0;

    {   // K: convert + swizzle, row-major
        const float4* kr = (const float4*)(K + grow);
        float4 a = kr[0], b = kr[1], c = kr[2], d = kr[3];
        short* out = wsK + ((size_t)bh * kS + (size_t)kb * 64 + r) * kD;
        const int gi = c0 >> 3, s = r & 7;
        *(s16x8*)(out + (size_t)((gi    ) ^ s) * 8) = pack8(a, b);
        *(s16x8*)(out + (size_t)((gi + 1) ^ s) * 8) = pack8(c, d);
    }
    {   // V tile into LDS (fp32, padded)
        const float4* vr = (const float4*)(V + grow);
        float4 a = vr[0], b = vr[1], c = vr[2], d = vr[3];
        float t[16] = {a.x,a.y,a.z,a.w, b.x,b.y,b.z,b.w,
                       c.x,c.y,c.z,c.w, d.x,d.y,d.z,d.w};
        #pragma unroll
        for (int j = 0; j < 16; ++j) vt[r][c0 + j] = t[j];
    }
    __syncthreads();
    {   // V^T: convert + swizzle, [d][k] per 64-tile
        const int d  = tid >> 2;
        const int k0 = (tid & 3) * 16;
        s16x8 g0, g1;
        #pragma unroll
        for (int j = 0; j < 8; ++j) g0[j] = f2bf(vt[k0 + j][d]);
        #pragma unroll
        for (int j = 0; j < 8; ++j) g1[j] = f2bf(vt[k0 + 8 + j][d]);
        short* out = wsVT + (((size_t)bh * kT + kb) * 64 + d) * 64;
        const int gi = k0 >> 3, s = d & 7;
        *(s16x8*)(out + (size_t)((gi    ) ^ s) * 8) = g0;
        *(s16x8*)(out + (size_t)((gi + 1) ^ s) * 8) = g1;
    }
}

// ---------------- main: paired q-tiles, glds staging, swizzled ds_read -------
__global__ __launch_bounds__(256)
void attn_mfma2(const float* __restrict__ Q, const short* __restrict__ wsK,
                const short* __restrict__ wsVT, float* __restrict__ O)
{
    __shared__ short Kbuf[2][64 * 64];
    __shared__ short Vbuf[2][64 * 64];
    __shared__ short Pst[4][16][PPAD];

    const int tid  = threadIdx.x;
    const int lane = tid & 63;
    const int w    = tid >> 6;
    const int lo   = lane & 15;
    const int hi   = lane >> 4;

    // XCD-aware mapping: dispatch round-robins XCDs by linear id; give each
    // XCD 4 heads so K/V stay in its L2. 512 blocks = 8 xcd * 4 bh * 16 pairs.
    const int n   = (int)(blockIdx.y * gridDim.x + blockIdx.x);
    const int xcd = n & 7;
    const int j   = n >> 3;
    const int bh  = xcd * 4 + (j >> 4);
    const int pr  = j & 15;

    const char* Kroot = (const char*)(wsK + (size_t)bh * kS * kD);
    const char* Vroot = (const char*)(wsVT + (size_t)bh * kT * 64 * 64);
    const f32x4 zero4 = {0.f, 0.f, 0.f, 0.f};

    auto stage = [&](int kb, int b) {
        const char* ks = Kroot + (size_t)kb * 8192 + lane * 16;
        const char* vs = Vroot + (size_t)kb * 8192 + lane * 16;
        char* kl = (char*)&Kbuf[b][0];
        char* vl = (char*)&Vbuf[b][0];
        glds16(ks + (size_t)w * 1024,       kl + w * 1024);
        glds16(ks + (size_t)(w + 4) * 1024, kl + (w + 4) * 1024);
        glds16(vs + (size_t)w * 1024,       vl + w * 1024);
        glds16(vs + (size_t)(w + 4) * 1024, vl + (w + 4) * 1024);
    };

    #pragma unroll 1
    for (int ph = 0; ph < 2; ++ph) {
        const int qt = ph ? (kT - 1 - pr) : pr;   // paired: work = 33 tiles/block

        // Q A-fragments, pre-scaled into base-2 domain
        const float* Qr = Q + ((size_t)bh * kS + qt * 64 + w * 16 + lo) * kD;
        bf16x8 qfrag[2];
        #pragma unroll
        for (int dc = 0; dc < 2; ++dc) {
            const float4 a = *(const float4*)(Qr + dc * 32 + hi * 8);
            const float4 b = *(const float4*)(Qr + dc * 32 + hi * 8 + 4);
            bf16x8 f;
            f[0] = f2bf(a.x * kScaleLog2e); f[1] = f2bf(a.y * kScaleLog2e);
            f[2] = f2bf(a.z * kScaleLog2e); f[3] = f2bf(a.w * kScaleLog2e);
            f[4] = f2bf(b.x * kScaleLog2e); f[5] = f2bf(b.y * kScaleLog2e);
            f[6] = f2bf(b.z * kScaleLog2e); f[7] = f2bf(b.w * kScaleLog2e);
            qfrag[dc] = f;
        }

        f32x4 o[4] = {zero4, zero4, zero4, zero4};
        float m_[4] = {-1e30f, -1e30f, -1e30f, -1e30f};
        float l_[4] = {0.f, 0.f, 0.f, 0.f};

        stage(0, 0);
        __syncthreads();

        #pragma unroll 1
        for (int kb = 0; kb <= qt; ++kb) {
            const int b = kb & 1;
            if (kb < qt) stage(kb + 1, b ^ 1);

            // ---- S = Q K^T (swizzled reads)
            const char* Kb_ = (const char*)&Kbuf[b][0];
            f32x4 sacc[4] = {zero4, zero4, zero4, zero4};
            #pragma unroll
            for (int kk = 0; kk < 4; ++kk) {
                const int row = kk * 16 + lo;
                #pragma unroll
                for (int dc = 0; dc < 2; ++dc) {
                    const int a = (row * 128 + dc * 64 + hi * 16) ^ ((lo & 7) << 4);
                    const bf16x8 kf = *(const bf16x8*)(Kb_ + a);
                    sacc[kk] = __builtin_amdgcn_mfma_f32_16x16x32_bf16(
                        qfrag[dc], kf, sacc[kk], 0, 0, 0);
                }
            }

            if (kb == qt) {   // causal mask on diagonal tile
                #pragma unroll
                for (int kk = 0; kk < 4; ++kk)
                    #pragma unroll
                    for (int r = 0; r < 4; ++r)
                        if (kk * 16 + lo > w * 16 + hi * 4 + r) sacc[kk][r] = -1e30f;
            }

            // ---- online softmax (base-2)
            float nm[4], alpha[4];
            #pragma unroll
            for (int r = 0; r < 4; ++r) {
                float v = fmaxf(fmaxf(sacc[0][r], sacc[1][r]),
                                fmaxf(sacc[2][r], sacc[3][r]));
                v = fmaxf(v, __shfl_xor(v, 1));
                v = fmaxf(v, __shfl_xor(v, 2));
                v = fmaxf(v, __shfl_xor(v, 4));
                v = fmaxf(v, __shfl_xor(v, 8));
                nm[r]    = fmaxf(v, m_[r]);
                alpha[r] = exp2f(m_[r] - nm[r]);
            }
            float p[4][4];
            #pragma unroll
            for (int kk = 0; kk < 4; ++kk)
                #pragma unroll
                for (int r = 0; r < 4; ++r)
                    p[kk][r] = exp2f(sacc[kk][r] - nm[r]);
            #pragma unroll
            for (int r = 0; r < 4; ++r) {
                float s = (p[0][r] + p[1][r]) + (p[2][r] + p[3][r]);
                s += __shfl_xor(s, 1);
                s += __shfl_xor(s, 2);
                s += __shfl_xor(s, 4);
                s += __shfl_xor(s, 8);
                l_[r] = l_[r] * alpha[r] + s;
                m_[r] = nm[r];
            }
            #pragma unroll
            for (int dcB = 0; dcB < 4; ++dcB)
                #pragma unroll
                for (int r = 0; r < 4; ++r)
                    o[dcB][r] *= alpha[r];

            // ---- P transpose via per-wave LDS strip (intra-wave)
            #pragma unroll
            for (int kk = 0; kk < 4; ++kk)
                #pragma unroll
                for (int r = 0; r < 4; ++r)
                    Pst[w][hi * 4 + r][kk * 16 + lo] = f2bf(p[kk][r]);

            // ---- PV (swizzled V^T reads)
            const char* Vb_ = (const char*)&Vbuf[b][0];
            #pragma unroll
            for (int kc = 0; kc < 2; ++kc) {
                const bf16x8 pf = *(const bf16x8*)(
                    (const char*)&Pst[w][lo][0] + kc * 64 + hi * 16);
                #pragma unroll
                for (int dcB = 0; dcB < 4; ++dcB) {
                    const int row = dcB * 16 + lo;
                    const int a = (row * 128 + kc * 64 + hi * 16) ^ ((lo & 7) << 4);
                    const bf16x8 vf = *(const bf16x8*)(Vb_ + a);
                    o[dcB] = __builtin_amdgcn_mfma_f32_16x16x32_bf16(
                        pf, vf, o[dcB], 0, 0, 0);
                }
            }
            __syncthreads();
        }

        // ---- epilogue
        float* Ob = O + (size_t)bh * kS * kD;
        #pragma unroll
        for (int r = 0; r < 4; ++r) {
            const float inv = 1.0f / l_[r];
            const size_t q = (size_t)(qt * 64 + w * 16 + hi * 4 + r);
            #pragma unroll
            for (int dcB = 0; dcB < 4; ++dcB)
                Ob[q * kD + dcB * 16 + lo] = o[dcB][r] * inv;
        }
        __syncthreads();   // LDS reuse safety across phases
    }
}

// ---------------- fallback (R2 kernel, used only if ws too small) ------------
__global__ __launch_bounds__(256)
void attn_mfma(const float* __restrict__ Q, const float* __restrict__ K,
               const float* __restrict__ V, float* __restrict__ O)
{
    __shared__ short Klds[64 * PPAD];
    __shared__ short VTlds[64 * PPAD];
    __shared__ short Plds[4 * 16 * PPAD];

    const int tid  = threadIdx.x;
    const int lane = tid & 63;
    const int w    = tid >> 6;
    const int lo   = lane & 15;
    const int hi   = lane >> 4;
    const int qt = (int)gridDim.x - 1 - (int)blockIdx.x;
    const int bh = blockIdx.y;
    const size_t hbase = (size_t)bh * kS * kD;

    const float* Qr = Q + hbase + (size_t)(qt * 64 + w * 16 + lo) * kD;
    bf16x8 qfrag[2];
    #pragma unroll
    for (int dc = 0; dc < 2; ++dc) {
        const float4 a = *(const float4*)(Qr + dc * 32 + hi * 8);
        const float4 b = *(const float4*)(Qr + dc * 32 + hi * 8 + 4);
        bf16x8 f;
        f[0] = f2bf(a.x * kScaleLog2e); f[1] = f2bf(a.y * kScaleLog2e);
        f[2] = f2bf(a.z * kScaleLog2e); f[3] = f2bf(a.w * kScaleLog2e);
        f[4] = f2bf(b.x * kScaleLog2e); f[5] = f2bf(b.y * kScaleLog2e);
        f[6] = f2bf(b.z * kScaleLog2e); f[7] = f2bf(b.w * kScaleLog2e);
        qfrag[dc] = f;
    }

    const f32x4 zero4 = {0.f, 0.f, 0.f, 0.f};
    f32x4 o[4] = {zero4, zero4, zero4, zero4};
    float m_[4] = {-1e30f, -1e30f, -1e30f, -1e30f};
    float l_[4] = {0.f, 0.f, 0.f, 0.f};
    const int sr = tid >> 2;
    const int sc = (tid & 3) * 16;
    const float* Kg = K + hbase;
    const float* Vg = V + hbase;
    short* Pw = &Plds[w * 16 * PPAD];

    for (int kb = 0; kb <= qt; ++kb) {
        __syncthreads();
        {
            const float* krow = Kg + (size_t)(kb * 64 + sr) * kD + sc;
            const float* vrow = Vg + (size_t)(kb * 64 + sr) * kD + sc;
            #pragma unroll
            for (int i = 0; i < 4; ++i) {
                const float4 kv = ((const float4*)krow)[i];
                s16x4 ks;
                ks[0] = f2bf(kv.x); ks[1] = f2bf(kv.y);
                ks[2] = f2bf(kv.z); ks[3] = f2bf(kv.w);
                *(s16x4*)&Klds[sr * PPAD + sc + i * 4] = ks;
                const float4 vv = ((const float4*)vrow)[i];
                VTlds[(sc + i * 4 + 0) * PPAD + sr] = f2bf(vv.x);
                VTlds[(sc + i * 4 + 1) * PPAD + sr] = f2bf(vv.y);
                VTlds[(sc + i * 4 + 2) * PPAD + sr] = f2bf(vv.z);
                VTlds[(sc + i * 4 + 3) * PPAD + sr] = f2bf(vv.w);
            }
        }
        __syncthreads();

        f32x4 sacc[4] = {zero4, zero4, zero4, zero4};
        #pragma unroll
        for (int kk = 0; kk < 4; ++kk)
            #pragma unroll
            for (int dc = 0; dc < 2; ++dc) {
                const bf16x8 kf = *(const bf16x8*)(
                    &Klds[(kk * 16 + lo) * PPAD + dc * 32 + hi * 8]);
                sacc[kk] = __builtin_amdgcn_mfma_f32_16x16x32_bf16(
                    qfrag[dc], kf, sacc[kk], 0, 0, 0);
            }
        if (kb == qt) {
            #pragma unroll
            for (int kk = 0; kk < 4; ++kk)
                #pragma unroll
                for (int r = 0; r < 4; ++r)
                    if (kk * 16 + lo > w * 16 + hi * 4 + r) sacc[kk][r] = -1e30f;
        }
        float nm[4], alpha[4];
        #pragma unroll
        for (int r = 0; r < 4; ++r) {
            float v = fmaxf(fmaxf(sacc[0][r], sacc[1][r]),
                            fmaxf(sacc[2][r], sacc[3][r]));
            v = fmaxf(v, __shfl_xor(v, 1));
            v = fmaxf(v, __shfl_xor(v, 2));
            v = fmaxf(v, __shfl_xor(v, 4));
            v = fmaxf(v, __shfl_xor(v, 8));
            nm[r]    = fmaxf(v, m_[r]);
            alpha[r] = exp2f(m_[r] - nm[r]);
        }
        float p[4][4];
        #pragma unroll
        for (int kk = 0; kk < 4; ++kk)
            #pragma unroll
            for (int r = 0; r < 4; ++r)
                p[kk][r] = exp2f(sacc[kk][r] - nm[r]);
        #pragma unroll
        for (int r = 0; r < 4; ++r) {
            float s = (p[0][r] + p[1][r]) + (p[2][r] + p[3][r]);
            s += __shfl_xor(s, 1);
            s += __shfl_xor(s, 2);
            s += __shfl_xor(s, 4);
            s += __shfl_xor(s, 8);
            l_[r] = l_[r] * alpha[r] + s;
            m_[r] = nm[r];
        }
        #pragma unroll
        for (int dcB = 0; dcB < 4; ++dcB)
            #pragma unroll
            for (int r = 0; r < 4; ++r)
                o[dcB][r] *= alpha[r];
        #pragma unroll
        for (int kk = 0; kk < 4; ++kk)
            #pragma unroll
            for (int r = 0; r < 4; ++r)
                Pw[(hi * 4 + r) * PPAD + kk * 16 + lo] = f2bf(p[kk][r]);
        #pragma unroll
        for (int kc = 0; kc < 2; ++kc) {
            const bf16x8 pf = *(const bf16x8*)(&Pw[lo * PPAD + kc * 32 + hi * 8]);
            #pragma unroll
            for (int dcB = 0; dcB < 4; ++dcB) {
                const bf16x8 vf = *(const bf16x8*)(
                    &VTlds[(dcB * 16 + lo) * PPAD + kc * 32 + hi * 8]);
                o[dcB] = __builtin_amdgcn_mfma_f32_16x16x32_bf16(
                    pf, vf, o[dcB], 0, 0, 0);
            }
        }
    }
    float* Ob = O + hbase;
    #pragma unroll
    for (int r = 0; r < 4; ++r) {
        const float inv = 1.0f / l_[r];
        const size_t q = (size_t)(qt * 64 + w * 16 + hi * 4 + r);
        #pragma unroll
        for (int dcB = 0; dcB < 4; ++dcB)
            Ob[q * kD + dcB * 16 + lo] = o[dcB][r] * inv;
    }
}

extern "C" void kernel_launch(void* const* d_in, const int* in_sizes, int n_in,
                              void* d_out, int out_size, void* d_ws, size_t ws_size,
                              hipStream_t stream) {
    const float* Q = (const float*)d_in[0];
    const float* K = (const float*)d_in[1];
    const float* V = (const float*)d_in[2];
    // d_in[3] (causal mask) is static tril: causality implemented directly.
    float* out = (float*)d_out;
    (void)in_sizes; (void)n_in; (void)out_size;

    const size_t elemsK = (size_t)kBH * kS * kD;          // bf16 elements
    const size_t need   = elemsK * 2 * sizeof(short);     // K + V^T
    if (ws_size >= need) {
        short* wsK  = (short*)d_ws;
        short* wsVT = wsK + elemsK;
        prepack<<<dim3(kT, kBH), 256, 0, stream>>>(K, V, wsK, wsVT);
        attn_mfma2<<<dim3(16, kBH), 256, 0, stream>>>(Q, wsK, wsVT, out);
    } else {
        attn_mfma<<<dim3(kT, kBH), 256, 0, stream>>>(Q, K, V, out);
    }
}

// Round 4
// 72.390 us; speedup vs baseline: 20.0086x; 1.2280x over previous
//
#include <hip/hip_runtime.h>
#include <math.h>

typedef __attribute__((ext_vector_type(8))) short bf16x8;
typedef __attribute__((ext_vector_type(8))) short s16x8;
typedef __attribute__((ext_vector_type(4))) short s16x4;
typedef __attribute__((ext_vector_type(4))) float f32x4;
typedef __attribute__((ext_vector_type(16))) float f32x16;

namespace {
constexpr int kS   = 2048;
constexpr int kD   = 64;
constexpr int kBH  = 32;
constexpr int kT   = kS / 64;          // 32 KV tiles of 64
constexpr int PPAD = 72;
constexpr float kScaleLog2e = 0.125f * 1.44269504088896340736f; // rsqrt(64)*log2(e)
}

__device__ __forceinline__ short f2bf(float f) {
    union { float f; unsigned u; } c; c.f = f;
    unsigned r = c.u + 0x7fffu + ((c.u >> 16) & 1u);   // RNE
    return (short)(r >> 16);
}

__device__ __forceinline__ s16x8 pack8(const float4& a, const float4& b) {
    s16x8 r;
    r[0] = f2bf(a.x); r[1] = f2bf(a.y); r[2] = f2bf(a.z); r[3] = f2bf(a.w);
    r[4] = f2bf(b.x); r[5] = f2bf(b.y); r[6] = f2bf(b.z); r[7] = f2bf(b.w);
    return r;
}

typedef const __attribute__((address_space(1))) void* gas_t;
typedef __attribute__((address_space(3))) void* las_t;
__device__ __forceinline__ void glds16(const void* g, void* l) {
    __builtin_amdgcn_global_load_lds((gas_t)g, (las_t)l, 16, 0, 0);
}

__device__ __forceinline__ unsigned cvtpk(float lo, float hi_) {
    unsigned r;
    asm("v_cvt_pk_bf16_f32 %0, %1, %2" : "=v"(r) : "v"(lo), "v"(hi_));
    return r;
}
// v_permlane32_swap_b32: vdst rows 2,3 (lanes 32-63) <-> vsrc rows 0,1 (lanes 0-31)
__device__ __forceinline__ void plswap(unsigned& a, unsigned& b) {
    asm("v_permlane32_swap_b32 %0, %1" : "+v"(a), "+v"(b));
}

// ---------------- pre-pass: K -> bf16 swizzled, V -> V^T bf16 swizzled -------
// Swizzle: within each 128B row, 16B-granule g stored at g ^ (row & 7).
__global__ __launch_bounds__(256)
void prepack(const float* __restrict__ K, const float* __restrict__ V,
             short* __restrict__ wsK, short* __restrict__ wsVT)
{
    __shared__ float vt[64][65];
    const int tid = threadIdx.x;
    const int kb  = blockIdx.x;
    const int bh  = blockIdx.y;
    const int r   = tid >> 2;
    const int c0  = (tid & 3) * 16;

    const size_t grow = ((size_t)bh * kS + (size_t)kb * 64 + r) * kD + c0;

    {   // K: convert + swizzle, row-major
        const float4* kr = (const float4*)(K + grow);
        float4 a = kr[0], b = kr[1], c = kr[2], d = kr[3];
        short* out = wsK + ((size_t)bh * kS + (size_t)kb * 64 + r) * kD;
        const int gi = c0 >> 3, s = r & 7;
        *(s16x8*)(out + (size_t)((gi    ) ^ s) * 8) = pack8(a, b);
        *(s16x8*)(out + (size_t)((gi + 1) ^ s) * 8) = pack8(c, d);
    }
    {   // V tile into LDS (fp32, padded)
        const float4* vr = (const float4*)(V + grow);
        float4 a = vr[0], b = vr[1], c = vr[2], d = vr[3];
        float t[16] = {a.x,a.y,a.z,a.w, b.x,b.y,b.z,b.w,
                       c.x,c.y,c.z,c.w, d.x,d.y,d.z,d.w};
        #pragma unroll
        for (int j = 0; j < 16; ++j) vt[r][c0 + j] = t[j];
    }
    __syncthreads();
    {   // V^T: convert + swizzle, [d][k] per 64-tile
        const int d  = tid >> 2;
        const int k0 = (tid & 3) * 16;
        s16x8 g0, g1;
        #pragma unroll
        for (int j = 0; j < 8; ++j) g0[j] = f2bf(vt[k0 + j][d]);
        #pragma unroll
        for (int j = 0; j < 8; ++j) g1[j] = f2bf(vt[k0 + 8 + j][d]);
        short* out = wsVT + (((size_t)bh * kT + kb) * 64 + d) * 64;
        const int gi = k0 >> 3, s = d & 7;
        *(s16x8*)(out + (size_t)((gi    ) ^ s) * 8) = g0;
        *(s16x8*)(out + (size_t)((gi + 1) ^ s) * 8) = g1;
    }
}

// ---------------- main: swapped QK^T, in-register softmax, 32x32x16 ----------
// Block = 4 warps x 32 q-rows = 128 rows. Lane owns q = qb*128 + w*32 + (lane&31);
// lane and lane^32 share a q-row (hold complementary k/d halves).
__global__ __launch_bounds__(256)
void attn_mfma3(const float* __restrict__ Q, const short* __restrict__ wsK,
                const short* __restrict__ wsVT, float* __restrict__ O)
{
    __shared__ short Kbuf[2][64 * 64];
    __shared__ short Vbuf[2][64 * 64];

    const int tid  = threadIdx.x;
    const int lane = tid & 63;
    const int w    = tid >> 6;
    const int ql   = lane & 31;
    const int hi   = lane >> 5;

    // 512 blocks = 8 xcd * 4 bh * 16 qb; long blocks (qb=15) dispatched first.
    const int n   = (int)blockIdx.x;
    const int xcd = n & 7;
    const int j   = n >> 3;
    const int bh  = xcd * 4 + (j & 3);
    const int qb  = 15 - (j >> 2);
    const int nt  = 2 * qb + 2;

    const int qrow = qb * 128 + w * 32 + ql;   // lane's q within this head

    // ---- Q fragments (hoisted): qf[s] = Q[qrow][d = s*16 + hi*8 + 0..7], scaled
    const float* Qr = Q + ((size_t)bh * kS + qrow) * kD;
    bf16x8 qf[4];
    #pragma unroll
    for (int s = 0; s < 4; ++s) {
        const float4 a = *(const float4*)(Qr + s * 16 + hi * 8);
        const float4 b = *(const float4*)(Qr + s * 16 + hi * 8 + 4);
        bf16x8 f;
        f[0] = f2bf(a.x * kScaleLog2e); f[1] = f2bf(a.y * kScaleLog2e);
        f[2] = f2bf(a.z * kScaleLog2e); f[3] = f2bf(a.w * kScaleLog2e);
        f[4] = f2bf(b.x * kScaleLog2e); f[5] = f2bf(b.y * kScaleLog2e);
        f[6] = f2bf(b.z * kScaleLog2e); f[7] = f2bf(b.w * kScaleLog2e);
        qf[s] = f;
    }

    f32x16 zero16;
    #pragma unroll
    for (int c = 0; c < 16; ++c) zero16[c] = 0.f;

    f32x16 o[2] = {zero16, zero16};   // O^T acc: q=lane&31, d=(c&3)+8*(c>>2)+4*hi+32*dt
    float m_ = -1e30f, l_ = 0.f;

    const char* Kroot = (const char*)(wsK + (size_t)bh * kS * kD);
    const char* Vroot = (const char*)(wsVT + (size_t)bh * kT * 64 * 64);

    auto stage = [&](int kb, int b) {
        const char* ks = Kroot + (size_t)kb * 8192;
        const char* vs = Vroot + (size_t)kb * 8192;
        char* kl = (char*)&Kbuf[b][0];
        char* vl = (char*)&Vbuf[b][0];
        glds16(ks + tid * 16,        kl + tid * 16);
        glds16(ks + 4096 + tid * 16, kl + 4096 + tid * 16);
        glds16(vs + tid * 16,        vl + tid * 16);
        glds16(vs + 4096 + tid * 16, vl + 4096 + tid * 16);
    };

    stage(0, 0);
    __syncthreads();

    #pragma unroll 1
    for (int kb = 0; kb < nt; ++kb) {
        const int b = kb & 1;
        if (kb + 1 < nt) stage(kb + 1, b ^ 1);

        // warp computes iff tile overlaps its causal range
        if (kb * 64 <= qb * 128 + w * 32 + 31) {
            const char* Kb_ = (const char*)&Kbuf[b][0];
            const char* Vb_ = (const char*)&Vbuf[b][0];

            // ---- S^T = mfma(K, Q): lane holds S[k(c,hi)][q=ql] for kt=0,1
            f32x16 sacc[2] = {zero16, zero16};
            #pragma unroll
            for (int kt = 0; kt < 2; ++kt) {
                #pragma unroll
                for (int s = 0; s < 4; ++s) {
                    const int a = (((kt * 32 + ql) * 128) + s * 32 + hi * 16)
                                  ^ ((ql & 7) << 4);
                    const bf16x8 kf = *(const bf16x8*)(Kb_ + a);
                    sacc[kt] = __builtin_amdgcn_mfma_f32_32x32x16_bf16(
                        kf, qf[s], sacc[kt], 0, 0, 0);
                }
            }

            // ---- causal mask (diagonal region only)
            if (kb * 64 + 63 > qb * 128 + w * 32) {
                #pragma unroll
                for (int kt = 0; kt < 2; ++kt) {
                    const int kbase = kb * 64 + kt * 32 + 4 * hi;
                    #pragma unroll
                    for (int c = 0; c < 16; ++c) {
                        const int kg = kbase + (c & 3) + 8 * (c >> 2);
                        if (kg > qrow) sacc[kt][c] = -1e30f;
                    }
                }
            }

            // ---- in-register online softmax (base-2), defer-max THR=8
            float pmax = -1e30f;
            #pragma unroll
            for (int kt = 0; kt < 2; ++kt) {
                float t0 = fmaxf(sacc[kt][0], sacc[kt][1]);
                float t1 = fmaxf(sacc[kt][2], sacc[kt][3]);
                float t2 = fmaxf(sacc[kt][4], sacc[kt][5]);
                float t3 = fmaxf(sacc[kt][6], sacc[kt][7]);
                float t4 = fmaxf(sacc[kt][8], sacc[kt][9]);
                float t5 = fmaxf(sacc[kt][10], sacc[kt][11]);
                float t6 = fmaxf(sacc[kt][12], sacc[kt][13]);
                float t7 = fmaxf(sacc[kt][14], sacc[kt][15]);
                float u0 = fmaxf(fmaxf(t0, t1), fmaxf(t2, t3));
                float u1 = fmaxf(fmaxf(t4, t5), fmaxf(t6, t7));
                pmax = fmaxf(pmax, fmaxf(u0, u1));
            }
            pmax = fmaxf(pmax, __shfl_xor(pmax, 32));   // partner holds other k-half

            if (__any(pmax > m_ + 8.0f)) {              // wave-uniform rescale
                const float nm    = fmaxf(m_, pmax);
                const float alpha = exp2f(m_ - nm);
                l_ *= alpha;
                #pragma unroll
                for (int dt = 0; dt < 2; ++dt)
                    #pragma unroll
                    for (int c = 0; c < 16; ++c) o[dt][c] *= alpha;
                m_ = nm;
            }

            // p = exp2(s - m_), in place; row-sum for l
            float psum = 0.f;
            #pragma unroll
            for (int kt = 0; kt < 2; ++kt)
                #pragma unroll
                for (int c = 0; c < 16; ++c) {
                    const float p = exp2f(sacc[kt][c] - m_);
                    sacc[kt][c] = p;
                    psum += p;
                }
            psum += __shfl_xor(psum, 32);
            l_ += psum;

            // ---- P -> bf16 B-frags via cvt_pk + permlane32_swap; PV accumulate
            #pragma unroll
            for (int kt = 0; kt < 2; ++kt) {
                unsigned w8[8];
                #pragma unroll
                for (int i = 0; i < 8; ++i)
                    w8[i] = cvtpk(sacc[kt][2 * i], sacc[kt][2 * i + 1]);
                #pragma unroll
                for (int s = 0; s < 2; ++s) {
                    unsigned A0 = w8[4 * s + 0], B0 = w8[4 * s + 2];
                    unsigned A1 = w8[4 * s + 1], B1 = w8[4 * s + 3];
                    plswap(A0, B0);
                    plswap(A1, B1);
                    union { unsigned u[4]; bf16x8 v; } pk;
                    pk.u[0] = A0; pk.u[1] = A1; pk.u[2] = B0; pk.u[3] = B1;
                    #pragma unroll
                    for (int dt = 0; dt < 2; ++dt) {
                        const int a = (((dt * 32 + ql) * 128) + kt * 64 + s * 32
                                       + hi * 16) ^ ((ql & 7) << 4);
                        const bf16x8 vf = *(const bf16x8*)(Vb_ + a);
                        o[dt] = __builtin_amdgcn_mfma_f32_32x32x16_bf16(
                            vf, pk.v, o[dt], 0, 0, 0);
                    }
                }
            }
        }
        __syncthreads();
    }

    // ---- epilogue: normalize, store fp32 (lane writes its q-row's hi-half)
    const float inv = 1.0f / l_;
    float* Ob = O + ((size_t)bh * kS + qrow) * kD;
    #pragma unroll
    for (int dt = 0; dt < 2; ++dt)
        #pragma unroll
        for (int t = 0; t < 4; ++t) {
            float4 v;
            v.x = o[dt][4 * t + 0] * inv;
            v.y = o[dt][4 * t + 1] * inv;
            v.z = o[dt][4 * t + 2] * inv;
            v.w = o[dt][4 * t + 3] * inv;
            *(float4*)(Ob + dt * 32 + 4 * hi + 8 * t) = v;
        }
}

// ---------------- fallback (R2 kernel, used only if ws too small) ------------
__global__ __launch_bounds__(256)
void attn_mfma(const float* __restrict__ Q, const float* __restrict__ K,
               const float* __restrict__ V, float* __restrict__ O)
{
    __shared__ short Klds[64 * PPAD];
    __shared__ short VTlds[64 * PPAD];
    __shared__ short Plds[4 * 16 * PPAD];

    const int tid  = threadIdx.x;
    const int lane = tid & 63;
    const int w    = tid >> 6;
    const int lo   = lane & 15;
    const int hi   = lane >> 4;
    const int qt = (int)gridDim.x - 1 - (int)blockIdx.x;
    const int bh = blockIdx.y;
    const size_t hbase = (size_t)bh * kS * kD;

    const float* Qr = Q + hbase + (size_t)(qt * 64 + w * 16 + lo) * kD;
    bf16x8 qfrag[2];
    #pragma unroll
    for (int dc = 0; dc < 2; ++dc) {
        const float4 a = *(const float4*)(Qr + dc * 32 + hi * 8);
        const float4 b = *(const float4*)(Qr + dc * 32 + hi * 8 + 4);
        bf16x8 f;
        f[0] = f2bf(a.x * kScaleLog2e); f[1] = f2bf(a.y * kScaleLog2e);
        f[2] = f2bf(a.z * kScaleLog2e); f[3] = f2bf(a.w * kScaleLog2e);
        f[4] = f2bf(b.x * kScaleLog2e); f[5] = f2bf(b.y * kScaleLog2e);
        f[6] = f2bf(b.z * kScaleLog2e); f[7] = f2bf(b.w * kScaleLog2e);
        qfrag[dc] = f;
    }

    const f32x4 zero4 = {0.f, 0.f, 0.f, 0.f};
    f32x4 o[4] = {zero4, zero4, zero4, zero4};
    float m_[4] = {-1e30f, -1e30f, -1e30f, -1e30f};
    float l_[4] = {0.f, 0.f, 0.f, 0.f};
    const int sr = tid >> 2;
    const int sc = (tid & 3) * 16;
    const float* Kg = K + hbase;
    const float* Vg = V + hbase;
    short* Pw = &Plds[w * 16 * PPAD];

    for (int kb = 0; kb <= qt; ++kb) {
        __syncthreads();
        {
            const float* krow = Kg + (size_t)(kb * 64 + sr) * kD + sc;
            const float* vrow = Vg + (size_t)(kb * 64 + sr) * kD + sc;
            #pragma unroll
            for (int i = 0; i < 4; ++i) {
                const float4 kv = ((const float4*)krow)[i];
                s16x4 ks;
                ks[0] = f2bf(kv.x); ks[1] = f2bf(kv.y);
                ks[2] = f2bf(kv.z); ks[3] = f2bf(kv.w);
                *(s16x4*)&Klds[sr * PPAD + sc + i * 4] = ks;
                const float4 vv = ((const float4*)vrow)[i];
                VTlds[(sc + i * 4 + 0) * PPAD + sr] = f2bf(vv.x);
                VTlds[(sc + i * 4 + 1) * PPAD + sr] = f2bf(vv.y);
                VTlds[(sc + i * 4 + 2) * PPAD + sr] = f2bf(vv.z);
                VTlds[(sc + i * 4 + 3) * PPAD + sr] = f2bf(vv.w);
            }
        }
        __syncthreads();

        f32x4 sacc[4] = {zero4, zero4, zero4, zero4};
        #pragma unroll
        for (int kk = 0; kk < 4; ++kk)
            #pragma unroll
            for (int dc = 0; dc < 2; ++dc) {
                const bf16x8 kf = *(const bf16x8*)(
                    &Klds[(kk * 16 + lo) * PPAD + dc * 32 + hi * 8]);
                sacc[kk] = __builtin_amdgcn_mfma_f32_16x16x32_bf16(
                    qfrag[dc], kf, sacc[kk], 0, 0, 0);
            }
        if (kb == qt) {
            #pragma unroll
            for (int kk = 0; kk < 4; ++kk)
                #pragma unroll
                for (int r = 0; r < 4; ++r)
                    if (kk * 16 + lo > w * 16 + hi * 4 + r) sacc[kk][r] = -1e30f;
        }
        float nm[4], alpha[4];
        #pragma unroll
        for (int r = 0; r < 4; ++r) {
            float v = fmaxf(fmaxf(sacc[0][r], sacc[1][r]),
                            fmaxf(sacc[2][r], sacc[3][r]));
            v = fmaxf(v, __shfl_xor(v, 1));
            v = fmaxf(v, __shfl_xor(v, 2));
            v = fmaxf(v, __shfl_xor(v, 4));
            v = fmaxf(v, __shfl_xor(v, 8));
            nm[r]    = fmaxf(v, m_[r]);
            alpha[r] = exp2f(m_[r] - nm[r]);
        }
        float p[4][4];
        #pragma unroll
        for (int kk = 0; kk < 4; ++kk)
            #pragma unroll
            for (int r = 0; r < 4; ++r)
                p[kk][r] = exp2f(sacc[kk][r] - nm[r]);
        #pragma unroll
        for (int r = 0; r < 4; ++r) {
            float s = (p[0][r] + p[1][r]) + (p[2][r] + p[3][r]);
            s += __shfl_xor(s, 1);
            s += __shfl_xor(s, 2);
            s += __shfl_xor(s, 4);
            s += __shfl_xor(s, 8);
            l_[r] = l_[r] * alpha[r] + s;
            m_[r] = nm[r];
        }
        #pragma unroll
        for (int dcB = 0; dcB < 4; ++dcB)
            #pragma unroll
            for (int r = 0; r < 4; ++r)
                o[dcB][r] *= alpha[r];
        #pragma unroll
        for (int kk = 0; kk < 4; ++kk)
            #pragma unroll
            for (int r = 0; r < 4; ++r)
                Pw[(hi * 4 + r) * PPAD + kk * 16 + lo] = f2bf(p[kk][r]);
        #pragma unroll
        for (int kc = 0; kc < 2; ++kc) {
            const bf16x8 pf = *(const bf16x8*)(&Pw[lo * PPAD + kc * 32 + hi * 8]);
            #pragma unroll
            for (int dcB = 0; dcB < 4; ++dcB) {
                const bf16x8 vf = *(const bf16x8*)(
                    &VTlds[(dcB * 16 + lo) * PPAD + kc * 32 + hi * 8]);
                o[dcB] = __builtin_amdgcn_mfma_f32_16x16x32_bf16(
                    pf, vf, o[dcB], 0, 0, 0);
            }
        }
    }
    float* Ob = O + hbase;
    #pragma unroll
    for (int r = 0; r < 4; ++r) {
        const float inv = 1.0f / l_[r];
        const size_t q = (size_t)(qt * 64 + w * 16 + hi * 4 + r);
        #pragma unroll
        for (int dcB = 0; dcB < 4; ++dcB)
            Ob[q * kD + dcB * 16 + lo] = o[dcB][r] * inv;
    }
}

extern "C" void kernel_launch(void* const* d_in, const int* in_sizes, int n_in,
                              void* d_out, int out_size, void* d_ws, size_t ws_size,
                              hipStream_t stream) {
    const float* Q = (const float*)d_in[0];
    const float* K = (const float*)d_in[1];
    const float* V = (const float*)d_in[2];
    // d_in[3] (causal mask) is static tril: causality implemented directly.
    float* out = (float*)d_out;
    (void)in_sizes; (void)n_in; (void)out_size;

    const size_t elemsK = (size_t)kBH * kS * kD;          // bf16 elements
    const size_t need   = elemsK * 2 * sizeof(short);     // K + V^T
    if (ws_size >= need) {
        short* wsK  = (short*)d_ws;
        short* wsVT = wsK + elemsK;
        prepack<<<dim3(kT, kBH), 256, 0, stream>>>(K, V, wsK, wsVT);
        attn_mfma3<<<dim3(512), 256, 0, stream>>>(Q, wsK, wsVT, out);
    } else {
        attn_mfma<<<dim3(kT, kBH), 256, 0, stream>>>(Q, K, V, out);
    }
}